// Round 13
// baseline (955.431 us; speedup 1.0000x reference)
//
#include <hip/hip_runtime.h>
#include <math.h>

#define A_TOT 8400
#define B_N   2
#define T_N   100
#define C_N   80
#define E_N   32
#define MH_N  64
#define MW_N  64
#define ROW_N 8363          // 4 + 80 + 85 + 4096 + 4098
#define NROWS (B_N*A_TOT)   // 16800
#define EPSF  1e-9f
#define COMP_CAP 1536       // positives per bt bounded by 1189 (grid mask)
#define NEGINF -1e30f

typedef float vfloat4 __attribute__((ext_vector_type(4)));

__device__ __forceinline__ float2 tmat_eval(
    float gx1, float gy1, float gx2, float gy2,
    float ax,  float ay,
    float px1, float py1, float px2, float py2,
    float cl, float atg, float atp) {
  float ix1 = fmaxf(gx1,px1), iy1 = fmaxf(gy1,py1);
  float ix2 = fminf(gx2,px2), iy2 = fminf(gy2,py2);
  float inter = fmaxf(ix2-ix1,0.f) * fmaxf(iy2-iy1,0.f);
  float wg = gx2-gx1, hg = gy2-gy1, wp = px2-px1, hp = py2-py1;
  float uni = wg*hg + wp*hp - inter + EPSF;
  float iou = inter / uni;
  float cw = fmaxf(gx2,px2) - fminf(gx1,px1);
  float ch = fmaxf(gy2,py2) - fminf(gy1,py1);
  float c2 = cw*cw + ch*ch + EPSF;
  float dx = gx1+gx2-px1-px2, dy = gy1+gy2-py1-py2;
  float rho2 = (dx*dx + dy*dy) * 0.25f;
  float da = atg - atp;
  float v  = 0.4052847345693511f * da * da;     // 4/pi^2
  float alpha = v / (1.f - iou + v + EPSF);
  float ciou = iou - rho2/c2 - alpha*v;
  float iouc = fminf(fmaxf(ciou, 0.f), 1.f);

  float tm = 0.f;
  if (ax > gx1 && ay > gy1 && ax < gx2 && ay < gy2) {   // strict grid mask
    float cp = 1.f / (1.f + expf(-cl));
    float i2 = iouc * iouc;
    tm = i2*i2*i2 * sqrtf(cp);                 // iou^6 * cls^0.5
  }
  return make_float2(tm, iouc);
}

// ---- kernel 1: per bt: full row CIoU -> tmat; kth/maxt/maxiou in-block ----
__global__ __launch_bounds__(512) void k_score(
    const float* __restrict__ cls_logits, const float* __restrict__ pred_boxes,
    const float* __restrict__ target_bbox, const int* __restrict__ target_cls,
    const float* __restrict__ anchors,
    float* __restrict__ tmat,
    float* __restrict__ kth, float* __restrict__ maxt, float* __restrict__ maxiou) {
  int bt   = blockIdx.x;
  int b    = bt / T_N;
  int tid  = threadIdx.x;
  int lane = tid & 63, wid = tid >> 6;
  __shared__ float comp[COMP_CAP];
  __shared__ float redm[8], redi[8];
  __shared__ float wtop[8][10];
  __shared__ int   cnt;
  if (tid == 0) cnt = 0;
  __syncthreads();

  float4 g  = *(const float4*)(target_bbox + bt*4);
  int    tc = target_cls[bt];
  float atg = atanf((g.z - g.x) / ((g.w - g.y) + EPSF));
  float* trow = tmat + (size_t)bt * A_TOT;

  float lm = 0.f, li = 0.f;
  for (int a = tid; a < A_TOT; a += 512) {
    float ax = anchors[a*2+0], ay = anchors[a*2+1];
    float4 pb = *(const float4*)(pred_boxes + ((size_t)(b*A_TOT+a))*4);
    float cl = cls_logits[((size_t)(b*A_TOT+a))*C_N + tc];
    float atp = atanf((pb.z - pb.x) / ((pb.w - pb.y) + EPSF));
    float2 r = tmat_eval(g.x,g.y,g.z,g.w, ax,ay, pb.x,pb.y,pb.z,pb.w,
                         cl, atg, atp);
    trow[a] = r.x;
    li = fmaxf(li, r.y);
    if (r.x > 0.f) {
      lm = fmaxf(lm, r.x);
      comp[atomicAdd(&cnt, 1)] = r.x;
    }
  }
  #pragma unroll
  for (int off = 32; off; off >>= 1) {
    lm = fmaxf(lm, __shfl_xor(lm, off));
    li = fmaxf(li, __shfl_xor(li, off));
  }
  if (lane == 0) { redm[wid] = lm; redi[wid] = li; }
  __syncthreads();
  if (tid == 0) {
    float m = redm[0], mi = redi[0];
    #pragma unroll
    for (int w = 1; w < 8; w++) { m = fmaxf(m, redm[w]); mi = fmaxf(mi, redi[w]); }
    maxt[bt] = m; maxiou[bt] = mi;
  }
  int count = cnt;   // safe: after __syncthreads

  // per-wave top-10 over its strided slice of comp (<=3 elems/lane, in regs)
  int base = wid*64 + lane;
  float e0 = (base        < count) ? comp[base]        : NEGINF;
  float e1 = (base + 512  < count) ? comp[base + 512]  : NEGINF;
  float e2 = (base + 1024 < count) ? comp[base + 1024] : NEGINF;
  float mytop = NEGINF;
  #pragma unroll
  for (int k = 0; k < 10; k++) {
    float bv = e0; int bs = 0;
    if (e1 > bv) { bv = e1; bs = 1; }
    if (e2 > bv) { bv = e2; bs = 2; }
    float v = bv; int id = (lane << 2) | bs;
    #pragma unroll
    for (int off = 32; off; off >>= 1) {
      float ov = __shfl_xor(v, off); int oid = __shfl_xor(id, off);
      if (ov > v || (ov == v && oid < id)) { v = ov; id = oid; }
    }
    if ((id >> 2) == lane) {           // winner removes its element
      int s = id & 3;
      if (s == 0) e0 = NEGINF; else if (s == 1) e1 = NEGINF; else e2 = NEGINF;
    }
    if (lane == k) mytop = v;
  }
  if (lane < 10) wtop[wid][lane] = mytop;
  __syncthreads();

  if (wid == 0) {                      // merge 80 candidates in wave 0
    int ia = lane, ib = 64 + lane;
    float f0 = wtop[ia/10][ia%10];
    float f1 = (ib < 80) ? wtop[ib/10][ib%10] : NEGINF;
    float cur = NEGINF;
    #pragma unroll
    for (int k = 0; k < 10; k++) {
      float bv = f0; int bs = 0;
      if (f1 > bv) { bv = f1; bs = 1; }
      float v = bv; int id = (lane << 1) | bs;
      #pragma unroll
      for (int off = 32; off; off >>= 1) {
        float ov = __shfl_xor(v, off); int oid = __shfl_xor(id, off);
        if (ov > v || (ov == v && oid < id)) { v = ov; id = oid; }
      }
      if ((id >> 1) == lane) { if ((id & 1) == 0) f0 = NEGINF; else f1 = NEGINF; }
      cur = v;
    }
    if (lane == 0) kth[bt] = fmaxf(cur, 0.f);   // <10 positives -> 0 (ref zero-pad)
  }
}

// ---- kernel 2: per row: assign (from stored tmat) + write whole row -------
__global__ __launch_bounds__(256) void k_row(
    const float* __restrict__ cls_logits, const float* __restrict__ pred_boxes,
    const float* __restrict__ mask_embs,  const float* __restrict__ protos,
    const float* __restrict__ t_masks,    const float* __restrict__ tmat,
    const float* __restrict__ kth, const float* __restrict__ maxt,
    const float* __restrict__ maxiou, const float* __restrict__ target_bbox,
    const int* __restrict__ target_cls, const float* __restrict__ scalers,
    float* __restrict__ out) {
  unsigned row = blockIdx.x;
  int b   = row >= (unsigned)A_TOT;
  int a   = (int)row - b*A_TOT;
  int tid = threadIdx.x;
  __shared__ float sv[128];
  __shared__ int   st[128];
  __shared__ float semb[E_N];
  __shared__ float ctx[10];

  // phase 1: assignment (bitwise-consistent: stored tmat vs kth from same values)
  if (tid < 128) {
    float v = 0.f; int tt = 0x7fff;
    if (tid < T_N) {
      int bt = b*T_N + tid;
      float tv = tmat[(size_t)bt*A_TOT + a];
      if (tv > 0.f && tv >= kth[bt]) { v = tv; tt = tid; }
    }
    sv[tid] = v; st[tid] = tt;
  }
  if (tid < E_N) semb[tid] = mask_embs[(size_t)row*E_N + tid];
  __syncthreads();
  if (tid < 64) {
    float v1 = sv[tid];    int t1 = st[tid];
    float v2 = sv[tid+64]; int t2 = st[tid+64];
    if (v2 > v1 || (v2 == v1 && t2 < t1)) { v1 = v2; t1 = t2; }
    #pragma unroll
    for (int off = 32; off; off >>= 1) {
      float ov = __shfl_xor(v1, off); int ot = __shfl_xor(t1, off);
      if (ov > v1 || (ov == v1 && ot < t1)) { v1 = ov; t1 = ot; }
    }
    if (tid == 0) {
      int anyv = v1 > 0.f;
      int u = anyv ? t1 : 0;
      int bu = b*T_N + u;
      float4 tb = *(const float4*)(target_bbox + bu*4);
      float ng = anyv ? v1 / (maxt[bu] + EPSF) * maxiou[bu] : 0.f;
      ctx[0]=tb.x; ctx[1]=tb.y; ctx[2]=tb.z; ctx[3]=tb.w;
      ctx[4]= anyv ? 1.f : 0.f; ctx[5]=ng; ctx[6]=scalers[a];
      ctx[7]= (tb.z-tb.x)*(tb.w-tb.y)/(640.f*640.f);
      ctx[8]=__int_as_float(u); ctx[9]=__int_as_float(target_cls[bu]);
    }
  }
  __syncthreads();
  float tb0=ctx[0], tb1=ctx[1], tb2=ctx[2], tb3=ctx[3];
  float vld=ctx[4], ng=ctx[5], s=ctx[6], area=ctx[7];
  int   u  =__float_as_int(ctx[8]), ct=__float_as_int(ctx[9]);
  bool valid = vld > 0.5f;
  float x1s=tb0*0.1f, y1s=tb1*0.1f, x2s=tb2*0.1f, y2s=tb3*0.1f;
  size_t base = (size_t)row * ROW_N;

  auto val = [&](unsigned p) -> float {
    if (p < 84u) {
      if (p < 4u) return pred_boxes[(size_t)row*4 + p] / s;
      return cls_logits[(size_t)row*C_N + (p-4u)];
    }
    if (p < 169u) {
      if (p < 88u) { float t=(p==84u)?tb0:((p==85u)?tb1:((p==86u)?tb2:tb3)); return t/s; }
      if (p == 88u) return vld;
      return (valid && (int)p - 89 == ct) ? ng : 0.f;
    }
    if (p < 4265u) {                    // seg_pred
      if (!valid) return 0.f;
      unsigned q = p - 169u; int h = q >> 6, w = q & 63;
      float fh = (float)h, fw = (float)w;
      if (!(fh >= y1s && fh < y2s && fw >= x1s && fw < x2s)) return 0.f;
      const float* pr = protos + ((size_t)((b*MH_N + h)*MW_N + w)) * E_N;
      float acc = 0.f;
      #pragma unroll
      for (int e = 0; e < E_N; e++) acc += semb[e] * pr[e];
      return 1.f / (1.f + expf(-acc));
    }
    if (p == 4265u) return area;
    if (p == 4266u) return vld;
    if (!valid) return 0.f;             // align_seg
    unsigned q = p - 4267u; int h = q >> 6, w = q & 63;
    float fh = (float)h, fw = (float)w;
    if (!(fh >= y1s && fh < y2s && fw >= x1s && fw < x2s)) return 0.f;
    return t_masks[((size_t)((b*MH_N + h)*MW_N + w)) * T_N + u];
  };

  // phase 2: write entire row. Each thread owns a 64B span (4 consecutive
  // float4) per iteration -> 4 back-to-back NT stores in the common case.
  unsigned head = (4u - ((row * (unsigned)ROW_N) & 3u)) & 3u;
  if (tid < (int)head) out[base + tid] = val(tid);
  unsigned vec_end = head + (((unsigned)ROW_N - head) & ~3u);
  for (unsigned p0 = head + 16u*(unsigned)tid; p0 < vec_end; p0 += 4096u) {
    unsigned lim = min(p0 + 16u, vec_end);
    bool purez = !valid && ((p0 >= 4267u) || (p0 >= 169u && p0 + 16u <= 4265u));
    if (purez) {
      #pragma unroll
      for (unsigned j = 0; j < 4; j++) {
        unsigned p = p0 + 4u*j;
        if (p < lim)
          __builtin_nontemporal_store((vfloat4)(0.f), (vfloat4*)(out + base + p));
      }
    } else {
      #pragma unroll
      for (unsigned j = 0; j < 4; j++) {
        unsigned p = p0 + 4u*j;
        if (p < lim) {
          vfloat4 o;
          bool pure4 = (p >= 4267u) || (p >= 169u && p + 4u <= 4265u);
          if (pure4 && !valid) {
            o = (vfloat4)(0.f);
          } else {
            o.x = val(p); o.y = val(p+1u); o.z = val(p+2u); o.w = val(p+3u);
          }
          __builtin_nontemporal_store(o, (vfloat4*)(out + base + p));
        }
      }
    }
  }
  unsigned tail_n = (unsigned)ROW_N - vec_end;     // 0..3
  if (tid >= 32 && tid < 32 + (int)tail_n)
    out[base + vec_end + (unsigned)(tid - 32)] = val(vec_end + (unsigned)(tid - 32));
}

extern "C" void kernel_launch(void* const* d_in, const int* in_sizes, int n_in,
                              void* d_out, int out_size, void* d_ws, size_t ws_size,
                              hipStream_t stream) {
  const float* cls_logits   = (const float*)d_in[0];
  const float* pred_boxes   = (const float*)d_in[1];
  const float* mask_embs    = (const float*)d_in[2];
  const float* protos       = (const float*)d_in[3];
  const int*   target_cls   = (const int*)  d_in[4];
  const float* target_bbox  = (const float*)d_in[5];
  const float* target_masks = (const float*)d_in[6];
  const float* anchors      = (const float*)d_in[7];
  const float* scalers      = (const float*)d_in[8];
  float* out = (float*)d_out;

  // ws layout (floats); ~6.7 MB total
  float* ws     = (float*)d_ws;
  float* tmat   = ws;                                  // 1,680,000
  float* kth    = tmat + (size_t)B_N*T_N*A_TOT;        // 200
  float* maxt   = kth + B_N*T_N;                       // 200
  float* maxiou = maxt + B_N*T_N;                      // 200

  k_score<<<B_N*T_N, 512, 0, stream>>>(cls_logits, pred_boxes, target_bbox,
                                       target_cls, anchors, tmat, kth, maxt, maxiou);
  k_row<<<NROWS, 256, 0, stream>>>(cls_logits, pred_boxes, mask_embs, protos,
                                   target_masks, tmat, kth, maxt, maxiou,
                                   target_bbox, target_cls, scalers, out);
}

// Round 14
// 178.358 us; speedup vs baseline: 5.3568x; 5.3568x over previous
//
#include <hip/hip_runtime.h>
#include <math.h>

#define A_TOT 8400
#define B_N   2
#define T_N   100
#define C_N   80
#define E_N   32
#define MH_N  64
#define MW_N  64
#define ROW_N 8363          // 4 + 80 + 85 + 4096 + 4098
#define NROWS (B_N*A_TOT)   // 16800
#define EPSF  1e-9f
#define COMP_CAP 1536       // positives per bt bounded by 1189 (grid mask)
#define NEGINF -1e30f

__device__ __forceinline__ float2 tmat_eval(
    float gx1, float gy1, float gx2, float gy2,
    float ax,  float ay,
    float px1, float py1, float px2, float py2,
    float cl, float atg, float atp) {
  float ix1 = fmaxf(gx1,px1), iy1 = fmaxf(gy1,py1);
  float ix2 = fminf(gx2,px2), iy2 = fminf(gy2,py2);
  float inter = fmaxf(ix2-ix1,0.f) * fmaxf(iy2-iy1,0.f);
  float wg = gx2-gx1, hg = gy2-gy1, wp = px2-px1, hp = py2-py1;
  float uni = wg*hg + wp*hp - inter + EPSF;
  float iou = inter / uni;
  float cw = fmaxf(gx2,px2) - fminf(gx1,px1);
  float ch = fmaxf(gy2,py2) - fminf(gy1,py1);
  float c2 = cw*cw + ch*ch + EPSF;
  float dx = gx1+gx2-px1-px2, dy = gy1+gy2-py1-py2;
  float rho2 = (dx*dx + dy*dy) * 0.25f;
  float da = atg - atp;
  float v  = 0.4052847345693511f * da * da;     // 4/pi^2
  float alpha = v / (1.f - iou + v + EPSF);
  float ciou = iou - rho2/c2 - alpha*v;
  float iouc = fminf(fmaxf(ciou, 0.f), 1.f);

  float tm = 0.f;
  if (ax > gx1 && ay > gy1 && ax < gx2 && ay < gy2) {   // strict grid mask
    float cp = 1.f / (1.f + expf(-cl));
    float i2 = iouc * iouc;
    tm = i2*i2*i2 * sqrtf(cp);                 // iou^6 * cls^0.5
  }
  return make_float2(tm, iouc);
}

// ---- kernel 1: per bt: full row CIoU -> tmat; kth/maxt/maxiou in-block ----
// (byte-identical to round 11's k_score)
__global__ __launch_bounds__(512) void k_score(
    const float* __restrict__ cls_logits, const float* __restrict__ pred_boxes,
    const float* __restrict__ target_bbox, const int* __restrict__ target_cls,
    const float* __restrict__ anchors,
    float* __restrict__ tmat,
    float* __restrict__ kth, float* __restrict__ maxt, float* __restrict__ maxiou) {
  int bt   = blockIdx.x;
  int b    = bt / T_N;
  int tid  = threadIdx.x;
  int lane = tid & 63, wid = tid >> 6;
  __shared__ float comp[COMP_CAP];
  __shared__ float redm[8], redi[8];
  __shared__ float wtop[8][10];
  __shared__ int   cnt;
  if (tid == 0) cnt = 0;
  __syncthreads();

  float4 g  = *(const float4*)(target_bbox + bt*4);
  int    tc = target_cls[bt];
  float atg = atanf((g.z - g.x) / ((g.w - g.y) + EPSF));
  float* trow = tmat + (size_t)bt * A_TOT;

  float lm = 0.f, li = 0.f;
  for (int a = tid; a < A_TOT; a += 512) {
    float ax = anchors[a*2+0], ay = anchors[a*2+1];
    float4 pb = *(const float4*)(pred_boxes + ((size_t)(b*A_TOT+a))*4);
    float cl = cls_logits[((size_t)(b*A_TOT+a))*C_N + tc];
    float atp = atanf((pb.z - pb.x) / ((pb.w - pb.y) + EPSF));
    float2 r = tmat_eval(g.x,g.y,g.z,g.w, ax,ay, pb.x,pb.y,pb.z,pb.w,
                         cl, atg, atp);
    trow[a] = r.x;
    li = fmaxf(li, r.y);
    if (r.x > 0.f) {
      lm = fmaxf(lm, r.x);
      comp[atomicAdd(&cnt, 1)] = r.x;
    }
  }
  #pragma unroll
  for (int off = 32; off; off >>= 1) {
    lm = fmaxf(lm, __shfl_xor(lm, off));
    li = fmaxf(li, __shfl_xor(li, off));
  }
  if (lane == 0) { redm[wid] = lm; redi[wid] = li; }
  __syncthreads();
  if (tid == 0) {
    float m = redm[0], mi = redi[0];
    #pragma unroll
    for (int w = 1; w < 8; w++) { m = fmaxf(m, redm[w]); mi = fmaxf(mi, redi[w]); }
    maxt[bt] = m; maxiou[bt] = mi;
  }
  int count = cnt;   // safe: after __syncthreads

  int base = wid*64 + lane;
  float e0 = (base        < count) ? comp[base]        : NEGINF;
  float e1 = (base + 512  < count) ? comp[base + 512]  : NEGINF;
  float e2 = (base + 1024 < count) ? comp[base + 1024] : NEGINF;
  float mytop = NEGINF;
  #pragma unroll
  for (int k = 0; k < 10; k++) {
    float bv = e0; int bs = 0;
    if (e1 > bv) { bv = e1; bs = 1; }
    if (e2 > bv) { bv = e2; bs = 2; }
    float v = bv; int id = (lane << 2) | bs;
    #pragma unroll
    for (int off = 32; off; off >>= 1) {
      float ov = __shfl_xor(v, off); int oid = __shfl_xor(id, off);
      if (ov > v || (ov == v && oid < id)) { v = ov; id = oid; }
    }
    if ((id >> 2) == lane) {
      int s = id & 3;
      if (s == 0) e0 = NEGINF; else if (s == 1) e1 = NEGINF; else e2 = NEGINF;
    }
    if (lane == k) mytop = v;
  }
  if (lane < 10) wtop[wid][lane] = mytop;
  __syncthreads();

  if (wid == 0) {
    int ia = lane, ib = 64 + lane;
    float f0 = wtop[ia/10][ia%10];
    float f1 = (ib < 80) ? wtop[ib/10][ib%10] : NEGINF;
    float cur = NEGINF;
    #pragma unroll
    for (int k = 0; k < 10; k++) {
      float bv = f0; int bs = 0;
      if (f1 > bv) { bv = f1; bs = 1; }
      float v = bv; int id = (lane << 1) | bs;
      #pragma unroll
      for (int off = 32; off; off >>= 1) {
        float ov = __shfl_xor(v, off); int oid = __shfl_xor(id, off);
        if (ov > v || (ov == v && oid < id)) { v = ov; id = oid; }
      }
      if ((id >> 1) == lane) { if ((id & 1) == 0) f0 = NEGINF; else f1 = NEGINF; }
      cur = v;
    }
    if (lane == 0) kth[bt] = fmaxf(cur, 0.f);   // <10 positives -> 0 (ref zero-pad)
  }
}

// ---- kernel 2: per row: assign + SPARSE write over memset-zeroed output ---
__global__ __launch_bounds__(256) void k_sparse(
    const float* __restrict__ cls_logits, const float* __restrict__ pred_boxes,
    const float* __restrict__ mask_embs,  const float* __restrict__ protos,
    const float* __restrict__ t_masks,    const float* __restrict__ tmat,
    const float* __restrict__ kth, const float* __restrict__ maxt,
    const float* __restrict__ maxiou, const float* __restrict__ target_bbox,
    const int* __restrict__ target_cls, const float* __restrict__ scalers,
    float* __restrict__ out) {
  unsigned row = blockIdx.x;
  int b   = row >= (unsigned)A_TOT;
  int a   = (int)row - b*A_TOT;
  int tid = threadIdx.x;
  __shared__ float sv[128];
  __shared__ int   st[128];
  __shared__ float semb[E_N];
  __shared__ float ctx[10];

  // phase 1: assignment (bitwise-consistent: stored tmat vs kth from same values)
  if (tid < 128) {
    float v = 0.f; int tt = 0x7fff;
    if (tid < T_N) {
      int bt = b*T_N + tid;
      float tv = tmat[(size_t)bt*A_TOT + a];
      if (tv > 0.f && tv >= kth[bt]) { v = tv; tt = tid; }
    }
    sv[tid] = v; st[tid] = tt;
  }
  if (tid < E_N) semb[tid] = mask_embs[(size_t)row*E_N + tid];
  __syncthreads();
  if (tid < 64) {
    float v1 = sv[tid];    int t1 = st[tid];
    float v2 = sv[tid+64]; int t2 = st[tid+64];
    if (v2 > v1 || (v2 == v1 && t2 < t1)) { v1 = v2; t1 = t2; }
    #pragma unroll
    for (int off = 32; off; off >>= 1) {
      float ov = __shfl_xor(v1, off); int ot = __shfl_xor(t1, off);
      if (ov > v1 || (ov == v1 && ot < t1)) { v1 = ov; t1 = ot; }
    }
    if (tid == 0) {
      int anyv = v1 > 0.f;
      int u = anyv ? t1 : 0;
      int bu = b*T_N + u;
      float4 tb = *(const float4*)(target_bbox + bu*4);
      float ng = anyv ? v1 / (maxt[bu] + EPSF) * maxiou[bu] : 0.f;
      ctx[0]=tb.x; ctx[1]=tb.y; ctx[2]=tb.z; ctx[3]=tb.w;
      ctx[4]= anyv ? 1.f : 0.f; ctx[5]=ng; ctx[6]=scalers[a];
      ctx[7]= (tb.z-tb.x)*(tb.w-tb.y)/(640.f*640.f);
      ctx[8]=__int_as_float(u); ctx[9]=__int_as_float(target_cls[bu]);
    }
  }
  __syncthreads();
  float tb0=ctx[0], tb1=ctx[1], tb2=ctx[2], tb3=ctx[3];
  float vld=ctx[4], ng=ctx[5], s=ctx[6], area=ctx[7];
  int   u  =__float_as_int(ctx[8]), ct=__float_as_int(ctx[9]);
  bool valid = vld > 0.5f;
  size_t base = (size_t)row * ROW_N;

  // phase 2a: small fields (positions 0..88 contiguous; 89+ct; 4265; 4266)
  if (tid < 92) {
    if (tid < 4)        out[base + tid] = pred_boxes[(size_t)row*4 + tid] / s;
    else if (tid < 84)  out[base + tid] = cls_logits[(size_t)row*C_N + (tid-4)];
    else if (tid < 88) {
      float t = (tid==84)?tb0:((tid==85)?tb1:((tid==86)?tb2:tb3));
      out[base + tid] = t / s;
    }
    else if (tid == 88) out[base + 88] = vld;
    else if (tid == 89) { if (valid) out[base + 89 + ct] = ng; }
    else if (tid == 90) out[base + 4265] = area;
    else                out[base + 4266] = vld;
  }
  if (!valid) return;

  // phase 2b: valid rows only — in-box seg_pred + align_seg
  float x1s=tb0*0.1f, y1s=tb1*0.1f, x2s=tb2*0.1f, y2s=tb3*0.1f;
  for (int p = tid; p < MH_N*MW_N; p += 256) {
    int h = p >> 6, w = p & 63;
    float fh = (float)h, fw = (float)w;
    if (fh >= y1s && fh < y2s && fw >= x1s && fw < x2s) {
      const float* pr = protos + ((size_t)((b*MH_N + h)*MW_N + w)) * E_N;
      float acc = 0.f;
      #pragma unroll
      for (int e = 0; e < E_N; e++) acc += semb[e] * pr[e];
      out[base + 169  + p] = 1.f / (1.f + expf(-acc));
      out[base + 4267 + p] = t_masks[((size_t)((b*MH_N + h)*MW_N + w)) * T_N + u];
    }
  }
}

extern "C" void kernel_launch(void* const* d_in, const int* in_sizes, int n_in,
                              void* d_out, int out_size, void* d_ws, size_t ws_size,
                              hipStream_t stream) {
  const float* cls_logits   = (const float*)d_in[0];
  const float* pred_boxes   = (const float*)d_in[1];
  const float* mask_embs    = (const float*)d_in[2];
  const float* protos       = (const float*)d_in[3];
  const int*   target_cls   = (const int*)  d_in[4];
  const float* target_bbox  = (const float*)d_in[5];
  const float* target_masks = (const float*)d_in[6];
  const float* anchors      = (const float*)d_in[7];
  const float* scalers      = (const float*)d_in[8];
  float* out = (float*)d_out;

  // ws layout (floats); ~6.7 MB total
  float* ws     = (float*)d_ws;
  float* tmat   = ws;                                  // 1,680,000
  float* kth    = tmat + (size_t)B_N*T_N*A_TOT;        // 200
  float* maxt   = kth + B_N*T_N;                       // 200
  float* maxiou = maxt + B_N*T_N;                      // 200

  hipMemsetAsync(out, 0, (size_t)out_size * sizeof(float), stream);
  k_score<<<B_N*T_N, 512, 0, stream>>>(cls_logits, pred_boxes, target_bbox,
                                       target_cls, anchors, tmat, kth, maxt, maxiou);
  k_sparse<<<NROWS, 256, 0, stream>>>(cls_logits, pred_boxes, mask_embs, protos,
                                      target_masks, tmat, kth, maxt, maxiou,
                                      target_bbox, target_cls, scalers, out);
}